// Round 7
// baseline (73.135 us; speedup 1.0000x reference)
//
#include <hip/hip_runtime.h>
#include <math.h>

#define K 4096           // time buckets; 16 KB LDS histogram
#define NHIST 1024       // histogram-role blocks (4 per CU -> 16 hist waves/CU)
#define NWORK 512        // streaming-role blocks (focal + reg)
#define NK1 (NHIST + NWORK)
#define NCOX 2048

// ---------------- K1: mixed-role — LDS histogram || focal+reg streaming -----
__global__ __launch_bounds__(256) void k1(
    const float* __restrict__ tm, const float* __restrict__ h, int n,
    const float* __restrict__ rp, const int* __restrict__ rl,
    const float* __restrict__ pw, int nw,
    const float* __restrict__ pb, int nb,
    float* __restrict__ btot, double* __restrict__ partW) {
    __shared__ __align__(8) float hist[K];
    int bid = blockIdx.x, tid = threadIdx.x;

    if (bid < NHIST) {
        // ---- histogram role: DS-pipe bound, 16 waves/CU keep it saturated ----
        int hidx = bid;
        for (int j = tid; j < K; j += 256) hist[j] = 0.f;
        __syncthreads();
        int per = n / NHIST;                       // 4096
        const float4* tm4 = (const float4*)(tm + (long long)hidx * per);
        const float4* h4  = (const float4*)(h  + (long long)hidx * per);
        int iters = per >> 2;                      // 1024
        for (int i = tid; i < iters; i += 256) {
            float4 t = tm4[i], hv = h4[i];
            unsigned b0 = (unsigned)(t.x * (float)K); if (b0 > K - 1u) b0 = K - 1u;
            unsigned b1 = (unsigned)(t.y * (float)K); if (b1 > K - 1u) b1 = K - 1u;
            unsigned b2 = (unsigned)(t.z * (float)K); if (b2 > K - 1u) b2 = K - 1u;
            unsigned b3 = (unsigned)(t.w * (float)K); if (b3 > K - 1u) b3 = K - 1u;
            atomicAdd(&hist[b0], __expf(hv.x));
            atomicAdd(&hist[b1], __expf(hv.y));
            atomicAdd(&hist[b2], __expf(hv.z));
            atomicAdd(&hist[b3], __expf(hv.w));
        }
        __syncthreads();
        // rotate flush start per block to spread global-atomic contention
        int rot = (bid & 255) << 4;
        for (int jj = tid; jj < K; jj += 256) {
            int j = (jj + rot) & (K - 1);
            float v = hist[j];
            if (v != 0.f) atomicAdd(&btot[j], v);   // coalesced, pre-zeroed
        }
    } else {
        // ---- streaming role: focal loss + L2 regularization ----
        int widx = bid - NHIST;                     // 0..NWORK-1
        int gtid = widx * 256 + tid;
        int stride = NWORK * 256;
        double foc = 0.0, reg = 0.0;

        int n4 = n >> 2;
        const float4* rp4 = (const float4*)rp;
        const int4*   rl4 = (const int4*)rl;
        for (int i = gtid; i < n4; i += stride) {
            float4 p = rp4[i];
            int4   l = rl4[i];
#define FOC(pc, lc)                                                           \
            {                                                                 \
                float pp = pc; float tt = (float)(lc);                        \
                float ce = fmaxf(pp, 0.f) - pp * tt                           \
                         + __logf(1.f + __expf(-fabsf(pp)));                  \
                float ptv = __expf(-ce); float om = 1.f - ptv;                \
                foc += (double)((0.25f * tt + 0.75f * (1.f - tt))             \
                                * om * om * ce);                              \
            }
            FOC(p.x, l.x) FOC(p.y, l.y) FOC(p.z, l.z) FOC(p.w, l.w)
#undef FOC
        }
        int nw4 = nw >> 2;
        const float4* pw4 = (const float4*)pw;
        for (int i = gtid; i < nw4; i += stride) {
            float4 v = pw4[i];
            reg += (double)v.x * v.x + (double)v.y * v.y
                 + (double)v.z * v.z + (double)v.w * v.w;
        }
        int nb4 = nb >> 2;
        const float4* pb4 = (const float4*)pb;
        if (gtid < nb4) {
            float4 v = pb4[gtid];
            reg += (double)v.x * v.x + (double)v.y * v.y
                 + (double)v.z * v.z + (double)v.w * v.w;
        }
        double* lds = (double*)hist;
        lds[tid] = foc; __syncthreads();
        for (int s = 128; s > 0; s >>= 1) { if (tid < s) lds[tid] += lds[tid + s]; __syncthreads(); }
        if (tid == 0) partW[widx * 2 + 0] = lds[0];
        __syncthreads();
        lds[tid] = reg; __syncthreads();
        for (int s = 128; s > 0; s >>= 1) { if (tid < s) lds[tid] += lds[tid + s]; __syncthreads(); }
        if (tid == 0) partW[widx * 2 + 1] = lds[0];
    }
}

// ---------------- kScan: single-block inclusive prefix, stores log ----------
__global__ __launch_bounds__(1024) void kScan(const float* __restrict__ btot,
                                              float* __restrict__ lpre) {
    __shared__ double lds[1024];
    int tid = threadIdx.x;
    float v[4];
    double s = 0.0;
    int base = tid * 4;
#pragma unroll
    for (int j = 0; j < 4; j++) { v[j] = btot[base + j]; s += (double)v[j]; }
    lds[tid] = s; __syncthreads();
    for (int off = 1; off < 1024; off <<= 1) {
        double a = (tid >= off) ? lds[tid - off] : 0.0;
        __syncthreads();
        lds[tid] += a;
        __syncthreads();
    }
    double run = (tid == 0) ? 0.0 : lds[tid - 1];
#pragma unroll
    for (int j = 0; j < 4; j++) {
        run += (double)v[j];
        lpre[base + j] = (float)log(run);   // -inf only in never-queried buckets
    }
}

// ---------------- kCox: per-event (h - log S) + n_events ---------------------
__global__ __launch_bounds__(256) void kCox(
    const float* __restrict__ tm, const float* __restrict__ h,
    const int* __restrict__ ev, int n,
    const float* __restrict__ lpre, double* __restrict__ partC) {
    int gtid = blockIdx.x * 256 + threadIdx.x;
    int stride = NCOX * 256;
    int n4 = n >> 2;
    const float4* tm4 = (const float4*)tm;
    const float4* h4  = (const float4*)h;
    const int4*   ev4 = (const int4*)ev;
    double cox = 0.0;
    int ne = 0;
#define CX(tc, hc, ec)                                                        \
        if (ec) {                                                             \
            unsigned b = (unsigned)((tc) * (float)K);                         \
            if (b > K - 1u) b = K - 1u;                                       \
            cox += (double)((hc) - lpre[b]);                                  \
            ne += 1;                                                          \
        }
    for (int i = gtid; i < n4; i += stride) {
        float4 t0 = tm4[i], h0 = h4[i];
        int4 e0 = ev4[i];
        CX(t0.x, h0.x, e0.x) CX(t0.y, h0.y, e0.y) CX(t0.z, h0.z, e0.z) CX(t0.w, h0.w, e0.w)
    }
#undef CX
    __shared__ double lds[256];
    int tid = threadIdx.x;
    lds[tid] = cox; __syncthreads();
    for (int s = 128; s > 0; s >>= 1) { if (tid < s) lds[tid] += lds[tid + s]; __syncthreads(); }
    if (tid == 0) partC[blockIdx.x * 2 + 0] = lds[0];
    __syncthreads();
    lds[tid] = (double)ne; __syncthreads();
    for (int s = 128; s > 0; s >>= 1) { if (tid < s) lds[tid] += lds[tid + s]; __syncthreads(); }
    if (tid == 0) partC[blockIdx.x * 2 + 1] = lds[0];
}

// ---------------- kFinal: reduce partials + combine --------------------------
__global__ __launch_bounds__(1024) void kFinal(
    const double* __restrict__ partC, const double* __restrict__ partW,
    const float* __restrict__ lsv, const float* __restrict__ lrv,
    const float* __restrict__ lgv, int n, float* __restrict__ out) {
    __shared__ double lds[1024];
    int tid = threadIdx.x;
    double cox = 0, ne = 0, foc = 0, reg = 0;
    for (int i = tid; i < NCOX; i += 1024) {
        cox += partC[i * 2 + 0];
        ne  += partC[i * 2 + 1];
    }
    for (int i = tid; i < NWORK; i += 1024) {
        foc += partW[i * 2 + 0];
        reg += partW[i * 2 + 1];
    }
    double coxT, neT, focT, regT;
    lds[tid] = cox; __syncthreads();
    for (int s = 512; s > 0; s >>= 1) { if (tid < s) lds[tid] += lds[tid + s]; __syncthreads(); }
    coxT = lds[0]; __syncthreads();
    lds[tid] = ne; __syncthreads();
    for (int s = 512; s > 0; s >>= 1) { if (tid < s) lds[tid] += lds[tid + s]; __syncthreads(); }
    neT = lds[0]; __syncthreads();
    lds[tid] = foc; __syncthreads();
    for (int s = 512; s > 0; s >>= 1) { if (tid < s) lds[tid] += lds[tid + s]; __syncthreads(); }
    focT = lds[0]; __syncthreads();
    lds[tid] = reg; __syncthreads();
    for (int s = 512; s > 0; s >>= 1) { if (tid < s) lds[tid] += lds[tid + s]; __syncthreads(); }
    regT = lds[0];
    if (tid == 0) {
        double surv = -coxT / (neT + 1e-8);
        double rec = focT / (double)n;
        double rg = 1e-4 * regT;
        double a = (double)lsv[0], b = (double)lrv[0], c = (double)lgv[0];
        double sp = exp(-a), rpv = exp(-b), gp = exp(-c);
        double total = sp * surv + rpv * rec + gp * rg + a + b + c;
        out[0] = (float)total;
        out[1] = (float)surv;
        out[2] = (float)rec;
        out[3] = (float)rg;
        out[4] = (float)sp;
        out[5] = (float)rpv;
    }
}

extern "C" void kernel_launch(void* const* d_in, const int* in_sizes, int n_in,
                              void* d_out, int out_size, void* d_ws, size_t ws_size,
                              hipStream_t stream) {
    const float* h   = (const float*)d_in[0];
    const float* rp  = (const float*)d_in[1];
    const float* tm  = (const float*)d_in[2];
    const int*   ev  = (const int*)d_in[3];
    const int*   rl  = (const int*)d_in[4];
    const float* pw  = (const float*)d_in[5];
    const float* pb  = (const float*)d_in[6];
    const float* lsv = (const float*)d_in[7];
    const float* lrv = (const float*)d_in[8];
    const float* lgv = (const float*)d_in[9];
    int n  = in_sizes[0];
    int nw = in_sizes[5];
    int nb = in_sizes[6];
    float* out = (float*)d_out;

    float*  btot  = (float*)d_ws;              // K floats
    float*  lpre  = btot + K;                  // K floats (log prefix)
    double* partW = (double*)(lpre + K);       // NWORK*2 doubles
    double* partC = partW + 2 * NWORK;         // NCOX*2 doubles

    hipMemsetAsync(btot, 0, (size_t)K * sizeof(float), stream);
    k1<<<NK1, 256, 0, stream>>>(tm, h, n, rp, rl, pw, nw, pb, nb, btot, partW);
    kScan<<<1, 1024, 0, stream>>>(btot, lpre);
    kCox<<<NCOX, 256, 0, stream>>>(tm, h, ev, n, lpre, partC);
    kFinal<<<1, 1024, 0, stream>>>(partC, partW, lsv, lrv, lgv, n, out);
}

// Round 8
// 61.108 us; speedup vs baseline: 1.1968x; 1.1968x over previous
//
#include <hip/hip_runtime.h>
#include <math.h>

#define K 2048           // time buckets; 8 KB LDS histogram
#define NHIST 256        // histogram-role blocks: 1 per CU, 1024 thr (16 waves)
#define NWORK 256        // streaming-role blocks (focal + reg), 1024 thr
#define NK1 (NHIST + NWORK)
#define NCOX 2048

// ---------------- K1: mixed-role — LDS histogram || focal+reg streaming -----
// Uniform 1024-thread blocks; round-robin dispatch puts 1 hist + 1 work per CU.
__global__ __launch_bounds__(1024) void k1(
    const float* __restrict__ tm, const float* __restrict__ h, int n,
    const float* __restrict__ rp, const int* __restrict__ rl,
    const float* __restrict__ pw, int nw,
    const float* __restrict__ pb, int nb,
    float* __restrict__ btot, double* __restrict__ partW) {
    __shared__ __align__(8) double sh[1024];      // 8 KB, shared by both roles
    int bid = blockIdx.x, tid = threadIdx.x;

    if (bid < NHIST) {
        // ---- histogram role: 16-wave feed of the LDS atomic unit ----
        float* hist = (float*)sh;                  // hist[K], K=2048
        for (int j = tid; j < K; j += 1024) hist[j] = 0.f;
        __syncthreads();
        int per = n / NHIST;                       // 16384
        const float4* tm4 = (const float4*)(tm + (long long)bid * per);
        const float4* h4  = (const float4*)(h  + (long long)bid * per);
        int iters = per >> 2;                      // 4096 -> 4 per thread
        for (int i = tid; i < iters; i += 1024) {
            float4 t = tm4[i], hv = h4[i];
            unsigned b0 = (unsigned)(t.x * (float)K); if (b0 > K - 1u) b0 = K - 1u;
            unsigned b1 = (unsigned)(t.y * (float)K); if (b1 > K - 1u) b1 = K - 1u;
            unsigned b2 = (unsigned)(t.z * (float)K); if (b2 > K - 1u) b2 = K - 1u;
            unsigned b3 = (unsigned)(t.w * (float)K); if (b3 > K - 1u) b3 = K - 1u;
            atomicAdd(&hist[b0], __expf(hv.x));
            atomicAdd(&hist[b1], __expf(hv.y));
            atomicAdd(&hist[b2], __expf(hv.z));
            atomicAdd(&hist[b3], __expf(hv.w));
        }
        __syncthreads();
        // flush: 0.5M coalesced global atomics total (256 blocks x 2048)
        for (int j = tid; j < K; j += 1024)
            atomicAdd(&btot[j], hist[j]);          // btot pre-zeroed
    } else {
        // ---- streaming role: focal loss + L2 regularization ----
        int widx = bid - NHIST;                     // 0..NWORK-1
        int gtid = widx * 1024 + tid;
        int stride = NWORK * 1024;                  // 262144
        double foc = 0.0, reg = 0.0;

        int n4 = n >> 2;
        const float4* rp4 = (const float4*)rp;
        const int4*   rl4 = (const int4*)rl;
        for (int i = gtid; i < n4; i += stride) {
            float4 p = rp4[i];
            int4   l = rl4[i];
#define FOC(pc, lc)                                                           \
            {                                                                 \
                float pp = pc; float tt = (float)(lc);                        \
                float ce = fmaxf(pp, 0.f) - pp * tt                           \
                         + __logf(1.f + __expf(-fabsf(pp)));                  \
                float ptv = __expf(-ce); float om = 1.f - ptv;                \
                foc += (double)((0.25f * tt + 0.75f * (1.f - tt))             \
                                * om * om * ce);                              \
            }
            FOC(p.x, l.x) FOC(p.y, l.y) FOC(p.z, l.z) FOC(p.w, l.w)
#undef FOC
        }
        int nw4 = nw >> 2;
        const float4* pw4 = (const float4*)pw;
        for (int i = gtid; i < nw4; i += stride) {
            float4 v = pw4[i];
            reg += (double)v.x * v.x + (double)v.y * v.y
                 + (double)v.z * v.z + (double)v.w * v.w;
        }
        int nb4 = nb >> 2;
        const float4* pb4 = (const float4*)pb;
        if (gtid < nb4) {
            float4 v = pb4[gtid];
            reg += (double)v.x * v.x + (double)v.y * v.y
                 + (double)v.z * v.z + (double)v.w * v.w;
        }
        double* lds = sh;
        lds[tid] = foc; __syncthreads();
        for (int s = 512; s > 0; s >>= 1) { if (tid < s) lds[tid] += lds[tid + s]; __syncthreads(); }
        if (tid == 0) partW[widx * 2 + 0] = lds[0];
        __syncthreads();
        lds[tid] = reg; __syncthreads();
        for (int s = 512; s > 0; s >>= 1) { if (tid < s) lds[tid] += lds[tid + s]; __syncthreads(); }
        if (tid == 0) partW[widx * 2 + 1] = lds[0];
    }
}

// ---------------- kScan: single-block inclusive prefix, stores log ----------
__global__ __launch_bounds__(1024) void kScan(const float* __restrict__ btot,
                                              float* __restrict__ lpre) {
    __shared__ double lds[1024];
    int tid = threadIdx.x;
    float v[2];
    double s = 0.0;
    int base = tid * 2;
#pragma unroll
    for (int j = 0; j < 2; j++) { v[j] = btot[base + j]; s += (double)v[j]; }
    lds[tid] = s; __syncthreads();
    for (int off = 1; off < 1024; off <<= 1) {
        double a = (tid >= off) ? lds[tid - off] : 0.0;
        __syncthreads();
        lds[tid] += a;
        __syncthreads();
    }
    double run = (tid == 0) ? 0.0 : lds[tid - 1];
#pragma unroll
    for (int j = 0; j < 2; j++) {
        run += (double)v[j];
        lpre[base + j] = (float)log(run);   // -inf only in never-queried buckets
    }
}

// ---------------- kCox: per-event (h - log S) + n_events ---------------------
__global__ __launch_bounds__(256) void kCox(
    const float* __restrict__ tm, const float* __restrict__ h,
    const int* __restrict__ ev, int n,
    const float* __restrict__ lpre, double* __restrict__ partC) {
    int gtid = blockIdx.x * 256 + threadIdx.x;
    int stride = NCOX * 256;
    int n4 = n >> 2;
    const float4* tm4 = (const float4*)tm;
    const float4* h4  = (const float4*)h;
    const int4*   ev4 = (const int4*)ev;
    double cox = 0.0;
    int ne = 0;
#define CX(tc, hc, ec)                                                        \
        if (ec) {                                                             \
            unsigned b = (unsigned)((tc) * (float)K);                         \
            if (b > K - 1u) b = K - 1u;                                       \
            cox += (double)((hc) - lpre[b]);                                  \
            ne += 1;                                                          \
        }
    for (int i = gtid; i < n4; i += stride) {
        float4 t0 = tm4[i], h0 = h4[i];
        int4 e0 = ev4[i];
        CX(t0.x, h0.x, e0.x) CX(t0.y, h0.y, e0.y) CX(t0.z, h0.z, e0.z) CX(t0.w, h0.w, e0.w)
    }
#undef CX
    __shared__ double lds[256];
    int tid = threadIdx.x;
    lds[tid] = cox; __syncthreads();
    for (int s = 128; s > 0; s >>= 1) { if (tid < s) lds[tid] += lds[tid + s]; __syncthreads(); }
    if (tid == 0) partC[blockIdx.x * 2 + 0] = lds[0];
    __syncthreads();
    lds[tid] = (double)ne; __syncthreads();
    for (int s = 128; s > 0; s >>= 1) { if (tid < s) lds[tid] += lds[tid + s]; __syncthreads(); }
    if (tid == 0) partC[blockIdx.x * 2 + 1] = lds[0];
}

// ---------------- kFinal: reduce partials + combine --------------------------
__global__ __launch_bounds__(1024) void kFinal(
    const double* __restrict__ partC, const double* __restrict__ partW,
    const float* __restrict__ lsv, const float* __restrict__ lrv,
    const float* __restrict__ lgv, int n, float* __restrict__ out) {
    __shared__ double lds[1024];
    int tid = threadIdx.x;
    double cox = 0, ne = 0, foc = 0, reg = 0;
    for (int i = tid; i < NCOX; i += 1024) {
        cox += partC[i * 2 + 0];
        ne  += partC[i * 2 + 1];
    }
    if (tid < NWORK) {
        foc = partW[tid * 2 + 0];
        reg = partW[tid * 2 + 1];
    }
    double coxT, neT, focT, regT;
    lds[tid] = cox; __syncthreads();
    for (int s = 512; s > 0; s >>= 1) { if (tid < s) lds[tid] += lds[tid + s]; __syncthreads(); }
    coxT = lds[0]; __syncthreads();
    lds[tid] = ne; __syncthreads();
    for (int s = 512; s > 0; s >>= 1) { if (tid < s) lds[tid] += lds[tid + s]; __syncthreads(); }
    neT = lds[0]; __syncthreads();
    lds[tid] = foc; __syncthreads();
    for (int s = 512; s > 0; s >>= 1) { if (tid < s) lds[tid] += lds[tid + s]; __syncthreads(); }
    focT = lds[0]; __syncthreads();
    lds[tid] = reg; __syncthreads();
    for (int s = 512; s > 0; s >>= 1) { if (tid < s) lds[tid] += lds[tid + s]; __syncthreads(); }
    regT = lds[0];
    if (tid == 0) {
        double surv = -coxT / (neT + 1e-8);
        double rec = focT / (double)n;
        double rg = 1e-4 * regT;
        double a = (double)lsv[0], b = (double)lrv[0], c = (double)lgv[0];
        double sp = exp(-a), rpv = exp(-b), gp = exp(-c);
        double total = sp * surv + rpv * rec + gp * rg + a + b + c;
        out[0] = (float)total;
        out[1] = (float)surv;
        out[2] = (float)rec;
        out[3] = (float)rg;
        out[4] = (float)sp;
        out[5] = (float)rpv;
    }
}

extern "C" void kernel_launch(void* const* d_in, const int* in_sizes, int n_in,
                              void* d_out, int out_size, void* d_ws, size_t ws_size,
                              hipStream_t stream) {
    const float* h   = (const float*)d_in[0];
    const float* rp  = (const float*)d_in[1];
    const float* tm  = (const float*)d_in[2];
    const int*   ev  = (const int*)d_in[3];
    const int*   rl  = (const int*)d_in[4];
    const float* pw  = (const float*)d_in[5];
    const float* pb  = (const float*)d_in[6];
    const float* lsv = (const float*)d_in[7];
    const float* lrv = (const float*)d_in[8];
    const float* lgv = (const float*)d_in[9];
    int n  = in_sizes[0];
    int nw = in_sizes[5];
    int nb = in_sizes[6];
    float* out = (float*)d_out;

    float*  btot  = (float*)d_ws;              // K floats
    float*  lpre  = btot + K;                  // K floats (log prefix)
    double* partW = (double*)(lpre + K);       // NWORK*2 doubles
    double* partC = partW + 2 * NWORK;         // NCOX*2 doubles

    hipMemsetAsync(btot, 0, (size_t)K * sizeof(float), stream);
    k1<<<NK1, 1024, 0, stream>>>(tm, h, n, rp, rl, pw, nw, pb, nb, btot, partW);
    kScan<<<1, 1024, 0, stream>>>(btot, lpre);
    kCox<<<NCOX, 256, 0, stream>>>(tm, h, ev, n, lpre, partC);
    kFinal<<<1, 1024, 0, stream>>>(partC, partW, lsv, lrv, lgv, n, out);
}